// Round 4
// baseline (245.237 us; speedup 1.0000x reference)
//
#include <hip/hip_runtime.h>
#include <stdint.h>
#include <stddef.h>

// ---------------------------------------------------------------------------
// BSplineKANLayer — R8 (resubmitted unchanged after R3 infra timeout).
// R7 post-mortem: XCD swizzle worked (FETCH 316->108MB, gemm no longer
// HBM-bound) but __syncthreads' implicit vmcnt(0) drained the prefetch each
// tile -> gemm 126us, MfmaUtil 25%. Prep ~110us vs 36us roofline
// (38016 tiny blocks, latency-bound).
// R8:
//   1. kan_gemm: counted-vmcnt 3-buffer pipeline (T4). Raw s_barrier +
//      "s_waitcnt vmcnt(4)" keeps 2 tiles of global_load_lds in flight
//      ACROSS barriers; never drains to 0 in the main loop.
//   2. kan_prep: grid-stride (2048 blocks), 2 uint4 outputs/thread.
// ---------------------------------------------------------------------------

typedef __attribute__((ext_vector_type(8))) _Float16 half8;  // 8 fp16 = 4 VGPRs
typedef __attribute__((ext_vector_type(4))) float f32x4;

#define IN_DIM   512
#define OUT_DIM  512
#define BATCH    16384
#define KCH      576     // uint4 chunks per row: 4608 fp16 = 576 * 16B

#define VMCNT(n) asm volatile("s_waitcnt vmcnt(" #n ")" ::: "memory")
#define FENCE()  asm volatile("" ::: "memory")

// RNE f32 -> fp16 pair packed in a uint (a low 16, b high 16)
__device__ __forceinline__ unsigned pk2(float a, float b) {
  _Float16 ha = (_Float16)a, hb = (_Float16)b;   // v_cvt_f16_f32 (RNE)
  unsigned short ua = __builtin_bit_cast(unsigned short, ha);
  unsigned short ub = __builtin_bit_cast(unsigned short, hb);
  return (unsigned)ua | ((unsigned)ub << 16);
}
__device__ __forceinline__ uint4 pk8(float4 a, float4 b) {
  uint4 r;
  r.x = pk2(a.x, a.y); r.y = pk2(a.z, a.w);
  r.z = pk2(b.x, b.y); r.w = pk2(b.z, b.w);
  return r;
}
__device__ __forceinline__ float4 silu4(float4 v) {
  float4 r;
  r.x = v.x / (1.f + __expf(-v.x));
  r.y = v.y / (1.f + __expf(-v.y));
  r.z = v.z / (1.f + __expf(-v.z));
  r.w = v.w / (1.f + __expf(-v.w));
  return r;
}

// Windowed cubic basis (uniform grid; matches reference's single-step-denom
// recursion exactly — verified R5/R6/R7): 8 fp16 values for one (row,dim).
__device__ __forceinline__ uint4 basis8(float xv, float g0, float rh) {
  float u  = (xv - g0) * rh;
  float tf = floorf(u);
  float f  = u - tf;
  int   t  = (int)tf;
  bool valid = (u >= 0.f) && (u < 11.f);
  t = min(max(t, 0), 10);
  float f2 = f * f, f3 = f2 * f;
  float omf = 1.f - f;
  float v0 = omf * omf * omf;                          // j = t-3
  float v1 = fmaf(f2, fmaf(3.f, f, -6.f), 4.f);        // j = t-2
  float v2 = fmaf(f, fmaf(f, fmaf(-3.f, f, 3.f), 3.f), 1.f);  // j = t-1
  float v3 = f3;                                       // j = t
  uint64_t pack = ((uint64_t)pk2(v2, v3) << 32) | (uint64_t)pk2(v0, v1);
  pack = valid ? pack : 0ull;
  const int base = 48 - 16 * t;
  uint4 r;
  uint32_t* rp = (uint32_t*)&r;
  #pragma unroll
  for (int i = 0; i < 4; ++i) {
    int amt = base + 32 * i;                           // in [-112, 48]
    uint32_t lo = (amt >= 0 && amt < 64) ? (uint32_t)(pack >> amt) : 0u;
    uint32_t hi = (amt < 0 && amt > -64) ? (uint32_t)(pack << (-amt)) : 0u;
    rp[i] = lo | hi;
  }
  return r;
}

// ===========================================================================
// Kernel 0: per-dim constants (g0, 1/softplus(gsl)) — computed ONCE per dim.
// ===========================================================================
__global__ __launch_bounds__(256) void kan_consts(
    const float* __restrict__ gsl, const float* __restrict__ gstart,
    float2* __restrict__ cst)
{
  int d = blockIdx.x * 256 + threadIdx.x;
  if (d < IN_DIM) {
    float v  = gsl[d * 11];                            // all 11 identical
    float sp = fmaxf(v, 0.f) + log1pf(expf(-fabsf(v)));  // softplus = step h
    cst[d] = make_float2(gstart[d], 1.f / sp);
  }
}

// ===========================================================================
// Kernel 1: prep, grid-stride, one PAIR of adjacent chunk-slots per thread.
// 288 pairs per row; slot pair (2k, 2k+1) never straddles the basis/silu
// boundary (512 is even). Chunk `slot` of row r stored at position
//   (slot & ~3) | (((slot&3) + ((r>>1)&3)) & 3)
// so the GEMM's linear global_load_lds + un-rotated ds_read is conflict-free.
// ===========================================================================
__global__ __launch_bounds__(256) void kan_prep(
    const float* __restrict__ x,       // (16384,512)
    const float* __restrict__ coeffs,  // (512,4096)
    const float* __restrict__ bwt,     // (512,512)
    const float2* __restrict__ cst,    // (512,) per-dim (g0, 1/h)
    uint4* __restrict__ A16,           // [16384][576]
    uint4* __restrict__ B16)           // [512][576]
{
  const int NP = (BATCH + OUT_DIM) * (KCH / 2);        // 4,866,048 pairs
  for (int p = blockIdx.x * 256 + threadIdx.x; p < NP; p += gridDim.x * 256) {
    int row = p / 288;
    int s0  = (p - row * 288) * 2;                     // even slot in [0,576)
    int rot, sw0, sw1;
    uint4 v0, v1;
    if (row < BATCH) {
      if (s0 < 512) {
        float2 xv = *(const float2*)(x + (size_t)row * IN_DIM + s0);
        float4 cc = *(const float4*)(cst + s0);        // (g0,rh) x 2 dims
        v0 = basis8(xv.x, cc.x, cc.y);
        v1 = basis8(xv.y, cc.z, cc.w);
      } else {
        const float* xs = x + (size_t)row * IN_DIM + (s0 - 512) * 8;
        float4 a = *(const float4*)(xs),     b = *(const float4*)(xs + 4);
        float4 c = *(const float4*)(xs + 8), d = *(const float4*)(xs + 12);
        v0 = pk8(silu4(a), silu4(b));
        v1 = pk8(silu4(c), silu4(d));
      }
      rot = (row >> 1) & 3;
      sw0 = (s0 & ~3) | (((s0 & 3) + rot) & 3);
      sw1 = (s0 & ~3) | ((((s0 & 3) + 1) + rot) & 3);
      A16[(size_t)row * KCH + sw0] = v0;
      A16[(size_t)row * KCH + sw1] = v1;
    } else {
      int n = row - BATCH;
      const float* sp = (s0 < 512)
          ? coeffs + (size_t)n * 4096 + s0 * 8
          : bwt    + (size_t)n * 512  + (s0 - 512) * 8;
      float4 a = *(const float4*)(sp),     b = *(const float4*)(sp + 4);
      float4 c = *(const float4*)(sp + 8), d = *(const float4*)(sp + 12);
      v0 = pk8(a, b);
      v1 = pk8(c, d);
      rot = (n >> 1) & 3;
      sw0 = (s0 & ~3) | (((s0 & 3) + rot) & 3);
      sw1 = (s0 & ~3) | ((((s0 & 3) + 1) + rot) & 3);
      B16[(size_t)n * KCH + sw0] = v0;
      B16[(size_t)n * KCH + sw1] = v1;
    }
  }
}

// ===========================================================================
// Kernel 2: GEMM. m97 structure + XCD swizzle + counted-vmcnt 3-buffer
// pipeline (T4): tiles t+1 and t+2 stay in flight across the barrier; the
// main loop never waits vmcnt(0). grid = 512 (1D swizzled), 256 thr,
// LDS 48 KB -> 2 blocks/CU.
// ===========================================================================
__device__ __forceinline__ void gload_lds16(const uint4* g, uint4* l) {
  __builtin_amdgcn_global_load_lds(
      (const __attribute__((address_space(1))) void*)g,
      (__attribute__((address_space(3))) void*)l, 16, 0, 0);
}

__global__ __launch_bounds__(256, 2) void kan_gemm(
    const uint4* __restrict__ A16,     // [16384][576] pre-swizzled fp16
    const uint4* __restrict__ B16,     // [512][576]   pre-swizzled fp16
    const float* __restrict__ x,       // (16384,512) for res_scale term
    const float* __restrict__ rsc,     // (1,)
    float* __restrict__ out)           // (16384,512)
{
  __shared__ uint4 As[3][512];         // [buf][128 rows][4 chunks]
  __shared__ uint4 Bs[3][512];

  const int tid  = threadIdx.x;
  const int lane = tid & 63;
  const int wv   = tid >> 6;

  // XCD-chunked bijective swizzle (512 % 8 == 0): XCD x gets m-panels
  // [x*16, x*16+16), each with all 4 n-blocks -> A-panel L2 reuse.
  const int bid  = blockIdx.x;
  const int wg   = ((bid & 7) << 6) | (bid >> 3);
  const int row0 = (wg >> 2) << 7;     // m-panel * 128
  const int n0   = (wg & 3) << 7;      // n-block * 128

  const int q    = lane >> 4;          // k-chunk 0..3
  const int l15  = lane & 15;
  const int wrow = (wv >> 1) << 6;
  const int wcol = (wv & 1) << 6;
  // read-side un-rotation: (r>>1)&3 == (l15>>1)&3 since wrow+tm*16 ≡ 0 mod 8
  const int cq   = (q + ((l15 >> 1) & 3)) & 3;

  // staging: wave wv fills tile slots [wv*128, wv*128+128), two halves of 64.
  const int s0 = wv * 128 + lane;
  const int s1 = s0 + 64;
  const uint4* ga0 = A16 + (size_t)(row0 + (s0 >> 2)) * KCH + (s0 & 3);
  const uint4* ga1 = A16 + (size_t)(row0 + (s1 >> 2)) * KCH + (s1 & 3);
  const uint4* gb0 = B16 + (size_t)(n0  + (s0 >> 2)) * KCH + (s0 & 3);
  const uint4* gb1 = B16 + (size_t)(n0  + (s1 >> 2)) * KCH + (s1 & 3);

  f32x4 acc[4][4];
  #pragma unroll
  for (int a = 0; a < 4; ++a)
    #pragma unroll
    for (int b = 0; b < 4; ++b)
      acc[a][b] = (f32x4){0.f, 0.f, 0.f, 0.f};

  auto stage = [&](int b, int kt) {     // 4 global_load_lds per wave
    const int o = kt * 4;               // 4 chunks = 64B per k-tile
    gload_lds16(ga0 + o, &As[b][wv * 128]);
    gload_lds16(ga1 + o, &As[b][wv * 128 + 64]);
    gload_lds16(gb0 + o, &Bs[b][wv * 128]);
    gload_lds16(gb1 + o, &Bs[b][wv * 128 + 64]);
  };
  auto compute = [&](int b) {
    half8 af[4], bg[4];
    #pragma unroll
    for (int tm = 0; tm < 4; ++tm)
      af[tm] = *(const half8*)&As[b][(wrow + tm * 16 + l15) * 4 + cq];
    #pragma unroll
    for (int tn = 0; tn < 4; ++tn)
      bg[tn] = *(const half8*)&Bs[b][(wcol + tn * 16 + l15) * 4 + cq];
    #pragma unroll
    for (int tm = 0; tm < 4; ++tm)
      #pragma unroll
      for (int tn = 0; tn < 4; ++tn)
        acc[tm][tn] = __builtin_amdgcn_mfma_f32_16x16x32_f16(
            af[tm], bg[tn], acc[tm][tn], 0, 0, 0);
  };

  // ---- prologue: tiles 0,1 issued; wait tile 0 only (vmcnt(4)) ----
  stage(0, 0);
  stage(1, 1);
  VMCNT(4);
  __builtin_amdgcn_s_barrier();
  FENCE();

  // ---- steady state: 47 groups of 3 (kt = 0..140), stages kt+2 <= 142 ----
  // invariant at STEP(b,kt) entry: buffer b = tile kt (drained); tile kt+1
  // in flight (4 loads); after: stage kt+2 issued, tile kt+1 drained.
  #define STEP(B, KT)                         \
    stage(((B) + 2) % 3, (KT) + 2);           \
    compute(B);                               \
    VMCNT(4);                                 \
    __builtin_amdgcn_s_barrier();             \
    FENCE();

  for (int k3 = 0; k3 < 47; ++k3) {
    const int kt = k3 * 3;
    STEP(0, kt);
    STEP(1, kt + 1);
    STEP(2, kt + 2);
  }
  // ---- epilogue: kt = 141,142,143 ----
  stage(2, 143);                       // in flight: 142(4) + 143(4)
  compute(0);                          // tile 141
  VMCNT(4);                            // tile 142 drained
  __builtin_amdgcn_s_barrier();
  FENCE();
  compute(1);                          // tile 142
  VMCNT(0);                            // tile 143 drained
  __builtin_amdgcn_s_barrier();
  FENCE();
  compute(2);                          // tile 143
  #undef STEP

  // epilogue: + res_scale * x, tanh, store. C/D: row=(lane>>4)*4+reg, col=l15
  const float rs = rsc[0];
  #pragma unroll
  for (int tm = 0; tm < 4; ++tm) {
    #pragma unroll
    for (int tn = 0; tn < 4; ++tn) {
      #pragma unroll
      for (int r = 0; r < 4; ++r) {
        int m = row0 + wrow + tm * 16 + q * 4 + r;
        int n = n0 + wcol + tn * 16 + l15;
        float xv = x[(size_t)m * IN_DIM + n];
        float y  = acc[tm][tn][r] + rs * xv;
        float e  = __expf(-2.f * fabsf(y));
        float t  = copysignf((1.f - e) / (1.f + e), y);
        out[(size_t)m * OUT_DIM + n] = t;
      }
    }
  }
}

// ===========================================================================
// Fallback: verified R5 fused kernel (used only if workspace is too small).
// ===========================================================================
__device__ __forceinline__ int swz(int r, int c) {
  return r * 4 + ((c + (r >> 1)) & 3);
}

__global__ __launch_bounds__(256, 2) void kan_main(
    const float* __restrict__ x, const float* __restrict__ coeffs,
    const float* __restrict__ bwt, const float* __restrict__ gsl,
    const float* __restrict__ gstart, const float* __restrict__ rsc,
    float* __restrict__ out)
{
  __shared__ uint4 At[512];
  __shared__ uint4 Bt[512];
  __shared__ float2 Cs[512];

  const int tid  = threadIdx.x;
  const int lane = tid & 63;
  const int wv   = tid >> 6;
  const int row0 = blockIdx.y << 7;
  const int n0   = blockIdx.x << 7;

  const int q    = lane >> 4;
  const int l15  = lane & 15;
  const int wrow = (wv >> 1) << 6;
  const int wcol = (wv & 1) << 6;

  for (int d = tid; d < IN_DIM; d += 256) {
    float v  = gsl[d * 11];
    float sp = fmaxf(v, 0.f) + log1pf(expf(-fabsf(v)));
    Cs[d] = make_float2(gstart[d], 1.f / sp);
  }
  __syncthreads();

  f32x4 acc[4][4];
  #pragma unroll
  for (int a = 0; a < 4; ++a)
    #pragma unroll
    for (int b = 0; b < 4; ++b)
      acc[a][b] = (f32x4){0.f, 0.f, 0.f, 0.f};

  const int br0 = tid >> 2,        bc0 = tid & 3;
  const int br1 = (tid + 256) >> 2, bc1 = tid & 3;

  auto do_mfma = [&]() {
    half8 af[4], bg[4];
    #pragma unroll
    for (int tm = 0; tm < 4; ++tm) {
      int m = wrow + tm * 16 + l15;
      af[tm] = *(const half8*)&At[swz(m, q)];
    }
    #pragma unroll
    for (int tn = 0; tn < 4; ++tn) {
      int n = wcol + tn * 16 + l15;
      bg[tn] = *(const half8*)&Bt[swz(n, q)];
    }
    #pragma unroll
    for (int tm = 0; tm < 4; ++tm)
      #pragma unroll
      for (int tn = 0; tn < 4; ++tn)
        acc[tm][tn] = __builtin_amdgcn_mfma_f32_16x16x32_f16(
            af[tm], bg[tn], acc[tm][tn], 0, 0, 0);
  };

  const float* bp0 = coeffs + (size_t)(n0 + br0) * 4096 + 1024 * bc0;
  const float* bp1 = coeffs + (size_t)(n0 + br1) * 4096 + 1024 * bc1;
  const float* xp0 = x + (size_t)(row0 + lane) * IN_DIM + 128 * wv;
  const float* xp1 = xp0 + (size_t)64 * IN_DIM;

  for (int kt4 = 0; kt4 < 32; ++kt4) {
    float4 xa = *(const float4*)(xp0 + kt4 * 4);
    float4 xb = *(const float4*)(xp1 + kt4 * 4);
    float xr0[4] = {xa.x, xa.y, xa.z, xa.w};
    float xr1[4] = {xb.x, xb.y, xb.z, xb.w};
    #pragma unroll
    for (int j = 0; j < 4; ++j) {
      const int kt = kt4 * 4 + j;
      const float* s0 = bp0 + kt * 8;
      const float* s1 = bp1 + kt * 8;
      float4 b0a = *(const float4*)(s0), b0b = *(const float4*)(s0 + 4);
      float4 b1a = *(const float4*)(s1), b1b = *(const float4*)(s1 + 4);

      float2 c = Cs[128 * wv + kt];
      uint4 p0 = basis8(xr0[j], c.x, c.y);
      uint4 p1 = basis8(xr1[j], c.x, c.y);

      Bt[swz(br0, bc0)] = pk8(b0a, b0b);
      Bt[swz(br1, bc1)] = pk8(b1a, b1b);
      At[swz(lane, wv)]      = p0;
      At[swz(lane + 64, wv)] = p1;
      __syncthreads();
      do_mfma();
      __syncthreads();
    }
  }

  for (int kt = 0; kt < 16; ++kt) {
    const int k0 = kt * 32;
    const float* s0 = bwt + (size_t)(n0 + br0) * 512 + k0 + bc0 * 8;
    const float* s1 = bwt + (size_t)(n0 + br1) * 512 + k0 + bc1 * 8;
    float4 b0a = *(const float4*)(s0), b0b = *(const float4*)(s0 + 4);
    float4 b1a = *(const float4*)(s1), b1b = *(const float4*)(s1 + 4);

    uint4 p[2];
    #pragma unroll
    for (int rr = 0; rr < 2; ++rr) {
      int idx = tid + rr * 256;
      int r = idx >> 2, cch = idx & 3;
      const float* xs = x + (size_t)(row0 + r) * IN_DIM + k0 + cch * 8;
      float4 xc = *(const float4*)(xs), xd = *(const float4*)(xs + 4);
      float f[8] = {xc.x, xc.y, xc.z, xc.w, xd.x, xd.y, xd.z, xd.w};
      #pragma unroll
      for (int jj = 0; jj < 8; ++jj) f[jj] = f[jj] / (1.f + __expf(-f[jj]));
      p[rr].x = pk2(f[0], f[1]); p[rr].y = pk2(f[2], f[3]);
      p[rr].z = pk2(f[4], f[5]); p[rr].w = pk2(f[6], f[7]);
    }

    Bt[swz(br0, bc0)] = pk8(b0a, b0b);
    Bt[swz(br1, bc1)] = pk8(b1a, b1b);
    #pragma unroll
    for (int rr = 0; rr < 2; ++rr) {
      int idx = tid + rr * 256;
      At[swz(idx >> 2, idx & 3)] = p[rr];
    }
    __syncthreads();
    do_mfma();
    __syncthreads();
  }

  const float rs = rsc[0];
  #pragma unroll
  for (int tm = 0; tm < 4; ++tm) {
    #pragma unroll
    for (int tn = 0; tn < 4; ++tn) {
      #pragma unroll
      for (int r = 0; r < 4; ++r) {
        int m = row0 + wrow + tm * 16 + q * 4 + r;
        int n = n0 + wcol + tn * 16 + l15;
        float xv = x[(size_t)m * IN_DIM + n];
        float y  = acc[tm][tn][r] + rs * xv;
        float e  = __expf(-2.f * fabsf(y));
        float t  = copysignf((1.f - e) / (1.f + e), y);
        out[(size_t)m * OUT_DIM + n] = t;
      }
    }
  }
}

// ---------------------------------------------------------------------------
extern "C" void kernel_launch(void* const* d_in, const int* in_sizes, int n_in,
                              void* d_out, int out_size, void* d_ws, size_t ws_size,
                              hipStream_t stream) {
  const float* x      = (const float*)d_in[0];
  const float* coeffs = (const float*)d_in[1];
  const float* bwt    = (const float*)d_in[2];
  const float* gsl    = (const float*)d_in[3];
  const float* gstart = (const float*)d_in[4];
  const float* rsc    = (const float*)d_in[5];
  float* out = (float*)d_out;
  (void)in_sizes; (void)n_in; (void)out_size;

  const size_t needA = (size_t)BATCH * KCH * 16;     // 150,994,944 B
  const size_t needB = (size_t)OUT_DIM * KCH * 16;   //   4,718,592 B
  const size_t needC = (size_t)IN_DIM * 8;           //       4,096 B

  if (d_ws != nullptr && ws_size >= needA + needB + needC) {
    uint4*  A16 = (uint4*)d_ws;
    uint4*  B16 = (uint4*)((char*)d_ws + needA);
    float2* cst = (float2*)((char*)d_ws + needA + needB);
    hipLaunchKernelGGL(kan_consts, dim3(2), dim3(256), 0, stream,
                       gsl, gstart, cst);
    hipLaunchKernelGGL(kan_prep, dim3(2048), dim3(256), 0, stream,
                       x, coeffs, bwt, (const float2*)cst, A16, B16);
    hipLaunchKernelGGL(kan_gemm, dim3(512), dim3(256), 0, stream,
                       (const uint4*)A16, (const uint4*)B16, x, rsc, out);
  } else {
    hipLaunchKernelGGL(kan_main, dim3(4, 128), dim3(256), 0, stream,
                       x, coeffs, bwt, gsl, gstart, rsc, out);
  }
}

// Round 5
// 214.370 us; speedup vs baseline: 1.1440x; 1.1440x over previous
//
#include <hip/hip_runtime.h>
#include <stdint.h>
#include <stddef.h>

// ---------------------------------------------------------------------------
// BSplineKANLayer — R9.
// R8 post-mortem: counted-vmcnt 3-buffer = null at 128²/4-wave (gemm 118 vs
// R6's 110) — T4 needs 8-phase role-split, confirmed regime-gate. Prep is
// ~125us vs 31us traffic floor (latency/issue-shaped; R8's grid-stride
// regressed it). R9:
//   1. kan_prep rewritten: block-per-2-rows, zero divisions, 4 independent
//      basis evals in flight per thread, dense coalesced uint4 stores.
//   2. kan_gemm reverted to R6's exact schedule (single 16KB buffer,
//      stage -> sync -> compute -> sync) + XCD swizzle kept as the ONLY
//      delta vs R6's measured 110us (isolates swizzle effect).
// ---------------------------------------------------------------------------

typedef __attribute__((ext_vector_type(8))) _Float16 half8;  // 8 fp16 = 4 VGPRs
typedef __attribute__((ext_vector_type(4))) float f32x4;

#define IN_DIM   512
#define OUT_DIM  512
#define BATCH    16384
#define KCH      576     // uint4 chunks per row: 4608 fp16 = 576 * 16B

// RNE f32 -> fp16 pair packed in a uint (a low 16, b high 16)
__device__ __forceinline__ unsigned pk2(float a, float b) {
  _Float16 ha = (_Float16)a, hb = (_Float16)b;   // v_cvt_f16_f32 (RNE)
  unsigned short ua = __builtin_bit_cast(unsigned short, ha);
  unsigned short ub = __builtin_bit_cast(unsigned short, hb);
  return (unsigned)ua | ((unsigned)ub << 16);
}
__device__ __forceinline__ uint4 pk8(float4 a, float4 b) {
  uint4 r;
  r.x = pk2(a.x, a.y); r.y = pk2(a.z, a.w);
  r.z = pk2(b.x, b.y); r.w = pk2(b.z, b.w);
  return r;
}
__device__ __forceinline__ float4 silu4(float4 v) {
  float4 r;
  r.x = v.x / (1.f + __expf(-v.x));
  r.y = v.y / (1.f + __expf(-v.y));
  r.z = v.z / (1.f + __expf(-v.z));
  r.w = v.w / (1.f + __expf(-v.w));
  return r;
}

// Windowed cubic basis (uniform grid; matches reference's single-step-denom
// recursion exactly — verified R5..R8): 8 fp16 values for one (row,dim).
__device__ __forceinline__ uint4 basis8(float xv, float g0, float rh) {
  float u  = (xv - g0) * rh;
  float tf = floorf(u);
  float f  = u - tf;
  int   t  = (int)tf;
  bool valid = (u >= 0.f) && (u < 11.f);
  t = min(max(t, 0), 10);
  float f2 = f * f, f3 = f2 * f;
  float omf = 1.f - f;
  float v0 = omf * omf * omf;                          // j = t-3
  float v1 = fmaf(f2, fmaf(3.f, f, -6.f), 4.f);        // j = t-2
  float v2 = fmaf(f, fmaf(f, fmaf(-3.f, f, 3.f), 3.f), 1.f);  // j = t-1
  float v3 = f3;                                       // j = t
  uint64_t pack = ((uint64_t)pk2(v2, v3) << 32) | (uint64_t)pk2(v0, v1);
  pack = valid ? pack : 0ull;
  const int base = 48 - 16 * t;
  uint4 r;
  uint32_t* rp = (uint32_t*)&r;
  #pragma unroll
  for (int i = 0; i < 4; ++i) {
    int amt = base + 32 * i;                           // in [-112, 48]
    uint32_t lo = (amt >= 0 && amt < 64) ? (uint32_t)(pack >> amt) : 0u;
    uint32_t hi = (amt < 0 && amt > -64) ? (uint32_t)(pack << (-amt)) : 0u;
    rp[i] = lo | hi;
  }
  return r;
}

// swizzled chunk position: rotate within each 4-chunk (64B) k-tile group.
__device__ __forceinline__ int swch(int slot, int rot) {
  return (slot & ~3) | (((slot & 3) + rot) & 3);
}

// ===========================================================================
// Kernel 0: per-dim constants (g0, 1/softplus(gsl)) — computed ONCE per dim.
// ===========================================================================
__global__ __launch_bounds__(256) void kan_consts(
    const float* __restrict__ gsl, const float* __restrict__ gstart,
    float2* __restrict__ cst)
{
  int d = blockIdx.x * 256 + threadIdx.x;
  if (d < IN_DIM) {
    float v  = gsl[d * 11];                            // all 11 identical
    float sp = fmaxf(v, 0.f) + log1pf(expf(-fabsf(v)));  // softplus = step h
    cst[d] = make_float2(gstart[d], 1.f / sp);
  }
}

// ===========================================================================
// Kernel 1: prep. Block b < 8192: A-rows (2b, 2b+1). Blocks 8192..8447:
// B-rows (2(b-8192), +1). Thread t handles slots {t, t+256} of both rows
// (basis/coeffs region), threads 0..127 handle the 64 silu/bwt slots x 2
// rows. All 4 main loads issued up-front (independent chains); stores are
// dense uint4, coalesced. rot = (row>>1)&3 is block-uniform (= b&3).
// ===========================================================================
__global__ __launch_bounds__(256) void kan_prep(
    const float* __restrict__ x,       // (16384,512)
    const float* __restrict__ coeffs,  // (512,4096)
    const float* __restrict__ bwt,     // (512,512)
    const float2* __restrict__ cst,    // (512,) per-dim (g0, 1/h)
    uint4* __restrict__ A16,           // [16384][576]
    uint4* __restrict__ B16)           // [512][576]
{
  const int tid = threadIdx.x;
  const int b   = blockIdx.x;

  if (b < 8192) {
    const int r0 = 2 * b, r1 = r0 + 1;
    const int rot = b & 3;                             // (row>>1)&3, both rows
    const float* xr0 = x + (size_t)r0 * IN_DIM;
    const float* xr1 = x + (size_t)r1 * IN_DIM;
    // --- 4 independent basis evals (slots tid, tid+256 of rows r0, r1) ---
    float x00 = xr0[tid], x01 = xr0[tid + 256];
    float x10 = xr1[tid], x11 = xr1[tid + 256];
    float2 c0 = cst[tid], c1 = cst[tid + 256];
    uint4 v00 = basis8(x00, c0.x, c0.y);
    uint4 v01 = basis8(x01, c1.x, c1.y);
    uint4 v10 = basis8(x10, c0.x, c0.y);
    uint4 v11 = basis8(x11, c1.x, c1.y);
    uint4* a0 = A16 + (size_t)r0 * KCH;
    uint4* a1 = A16 + (size_t)r1 * KCH;
    a0[swch(tid, rot)]       = v00;
    a0[swch(tid + 256, rot)] = v01;
    a1[swch(tid, rot)]       = v10;
    a1[swch(tid + 256, rot)] = v11;
    // --- silu tail: slots 512..575, rows r0/r1, threads 0..127 ---
    if (tid < 128) {
      int rr = tid >> 6;                               // 0 -> r0, 1 -> r1
      int j  = tid & 63;                               // slot 512+j
      const float* xs = (rr ? xr1 : xr0) + j * 8;
      float4 a = *(const float4*)(xs), bb = *(const float4*)(xs + 4);
      uint4 v = pk8(silu4(a), silu4(bb));
      uint4* ar = rr ? a1 : a0;
      ar[swch(512 + j, rot)] = v;
    }
  } else {
    const int bb = b - 8192;                           // 0..255
    const int n0 = 2 * bb, n1 = n0 + 1;
    const int rot = bb & 3;
    const float* c0 = coeffs + (size_t)n0 * 4096;
    const float* c1 = coeffs + (size_t)n1 * 4096;
    uint4* b0 = B16 + (size_t)n0 * KCH;
    uint4* b1 = B16 + (size_t)n1 * KCH;
    #pragma unroll
    for (int h = 0; h < 2; ++h) {
      int s = tid + h * 256;                           // slot in [0,512)
      const float* p0 = c0 + s * 8;
      const float* p1 = c1 + s * 8;
      float4 a0 = *(const float4*)(p0), a0b = *(const float4*)(p0 + 4);
      float4 a1 = *(const float4*)(p1), a1b = *(const float4*)(p1 + 4);
      b0[swch(s, rot)] = pk8(a0, a0b);
      b1[swch(s, rot)] = pk8(a1, a1b);
    }
    if (tid < 128) {
      int rr = tid >> 6;
      int j  = tid & 63;
      const float* ws = bwt + (size_t)(rr ? n1 : n0) * 512 + j * 8;
      float4 a = *(const float4*)(ws), bb2 = *(const float4*)(ws + 4);
      uint4 v = pk8(a, bb2);
      (rr ? b1 : b0)[swch(512 + j, rot)] = v;
    }
  }
}

// ===========================================================================
// Kernel 2: GEMM — R6's exact schedule (single 16KB buffer, stage -> sync ->
// compute -> sync) + XCD-chunked swizzle. grid = 512 (1D), 256 thr.
// ===========================================================================
__device__ __forceinline__ void gload_lds16(const uint4* g, uint4* l) {
  __builtin_amdgcn_global_load_lds(
      (const __attribute__((address_space(1))) void*)g,
      (__attribute__((address_space(3))) void*)l, 16, 0, 0);
}

__global__ __launch_bounds__(256, 2) void kan_gemm(
    const uint4* __restrict__ A16,     // [16384][576] pre-swizzled fp16
    const uint4* __restrict__ B16,     // [512][576]   pre-swizzled fp16
    const float* __restrict__ x,       // (16384,512) for res_scale term
    const float* __restrict__ rsc,     // (1,)
    float* __restrict__ out)           // (16384,512)
{
  __shared__ uint4 As[512];            // [128 rows][4 chunks], swizzled
  __shared__ uint4 Bs[512];

  const int tid  = threadIdx.x;
  const int lane = tid & 63;
  const int wv   = tid >> 6;

  // XCD-chunked bijective swizzle (512 % 8 == 0): XCD x gets m-panels
  // [x*16, x*16+16), each with all 4 n-blocks -> A-panel L2 reuse.
  const int bid  = blockIdx.x;
  const int wg   = ((bid & 7) << 6) | (bid >> 3);
  const int row0 = (wg >> 2) << 7;     // m-panel * 128
  const int n0   = (wg & 3) << 7;      // n-block * 128

  const int q    = lane >> 4;          // k-chunk 0..3
  const int l15  = lane & 15;
  const int wrow = (wv >> 1) << 6;
  const int wcol = (wv & 1) << 6;
  // read-side un-rotation: (r>>1)&3 == (l15>>1)&3 since wrow+tm*16 ≡ 0 mod 8
  const int cq   = (q + ((l15 >> 1) & 3)) & 3;

  // staging: wave wv fills tile slots [wv*128, wv*128+128), two halves of 64.
  const int s0 = wv * 128 + lane;
  const int s1 = s0 + 64;
  const uint4* ga0 = A16 + (size_t)(row0 + (s0 >> 2)) * KCH + (s0 & 3);
  const uint4* ga1 = A16 + (size_t)(row0 + (s1 >> 2)) * KCH + (s1 & 3);
  const uint4* gb0 = B16 + (size_t)(n0  + (s0 >> 2)) * KCH + (s0 & 3);
  const uint4* gb1 = B16 + (size_t)(n0  + (s1 >> 2)) * KCH + (s1 & 3);

  f32x4 acc[4][4];
  #pragma unroll
  for (int a = 0; a < 4; ++a)
    #pragma unroll
    for (int b = 0; b < 4; ++b)
      acc[a][b] = (f32x4){0.f, 0.f, 0.f, 0.f};

  for (int kt = 0; kt < 144; ++kt) {
    const int o = kt * 4;                      // 4 chunks = 64B per k-tile
    gload_lds16(ga0 + o, &As[wv * 128]);
    gload_lds16(ga1 + o, &As[wv * 128 + 64]);
    gload_lds16(gb0 + o, &Bs[wv * 128]);
    gload_lds16(gb1 + o, &Bs[wv * 128 + 64]);
    __syncthreads();                           // drains vmcnt(0)

    half8 af[4], bg[4];
    #pragma unroll
    for (int tm = 0; tm < 4; ++tm)
      af[tm] = *(const half8*)&As[(wrow + tm * 16 + l15) * 4 + cq];
    #pragma unroll
    for (int tn = 0; tn < 4; ++tn)
      bg[tn] = *(const half8*)&Bs[(wcol + tn * 16 + l15) * 4 + cq];
    #pragma unroll
    for (int tm = 0; tm < 4; ++tm)
      #pragma unroll
      for (int tn = 0; tn < 4; ++tn)
        acc[tm][tn] = __builtin_amdgcn_mfma_f32_16x16x32_f16(
            af[tm], bg[tn], acc[tm][tn], 0, 0, 0);
    __syncthreads();
  }

  // epilogue: + res_scale * x, tanh, store. C/D: row=(lane>>4)*4+reg, col=l15
  const float rs = rsc[0];
  #pragma unroll
  for (int tm = 0; tm < 4; ++tm) {
    #pragma unroll
    for (int tn = 0; tn < 4; ++tn) {
      #pragma unroll
      for (int r = 0; r < 4; ++r) {
        int m = row0 + wrow + tm * 16 + q * 4 + r;
        int n = n0 + wcol + tn * 16 + l15;
        float xv = x[(size_t)m * IN_DIM + n];
        float y  = acc[tm][tn][r] + rs * xv;
        float e  = __expf(-2.f * fabsf(y));
        float t  = copysignf((1.f - e) / (1.f + e), y);
        out[(size_t)m * OUT_DIM + n] = t;
      }
    }
  }
}

// ===========================================================================
// Fallback: verified R5 fused kernel (used only if workspace is too small).
// ===========================================================================
__device__ __forceinline__ int swz(int r, int c) {
  return r * 4 + ((c + (r >> 1)) & 3);
}

__global__ __launch_bounds__(256, 2) void kan_main(
    const float* __restrict__ x, const float* __restrict__ coeffs,
    const float* __restrict__ bwt, const float* __restrict__ gsl,
    const float* __restrict__ gstart, const float* __restrict__ rsc,
    float* __restrict__ out)
{
  __shared__ uint4 At[512];
  __shared__ uint4 Bt[512];
  __shared__ float2 Cs[512];

  const int tid  = threadIdx.x;
  const int lane = tid & 63;
  const int wv   = tid >> 6;
  const int row0 = blockIdx.y << 7;
  const int n0   = blockIdx.x << 7;

  const int q    = lane >> 4;
  const int l15  = lane & 15;
  const int wrow = (wv >> 1) << 6;
  const int wcol = (wv & 1) << 6;

  for (int d = tid; d < IN_DIM; d += 256) {
    float v  = gsl[d * 11];
    float sp = fmaxf(v, 0.f) + log1pf(expf(-fabsf(v)));
    Cs[d] = make_float2(gstart[d], 1.f / sp);
  }
  __syncthreads();

  f32x4 acc[4][4];
  #pragma unroll
  for (int a = 0; a < 4; ++a)
    #pragma unroll
    for (int b = 0; b < 4; ++b)
      acc[a][b] = (f32x4){0.f, 0.f, 0.f, 0.f};

  const int br0 = tid >> 2,        bc0 = tid & 3;
  const int br1 = (tid + 256) >> 2, bc1 = tid & 3;

  auto do_mfma = [&]() {
    half8 af[4], bg[4];
    #pragma unroll
    for (int tm = 0; tm < 4; ++tm) {
      int m = wrow + tm * 16 + l15;
      af[tm] = *(const half8*)&At[swz(m, q)];
    }
    #pragma unroll
    for (int tn = 0; tn < 4; ++tn) {
      int n = wcol + tn * 16 + l15;
      bg[tn] = *(const half8*)&Bt[swz(n, q)];
    }
    #pragma unroll
    for (int tm = 0; tm < 4; ++tm)
      #pragma unroll
      for (int tn = 0; tn < 4; ++tn)
        acc[tm][tn] = __builtin_amdgcn_mfma_f32_16x16x32_f16(
            af[tm], bg[tn], acc[tm][tn], 0, 0, 0);
  };

  const float* bp0 = coeffs + (size_t)(n0 + br0) * 4096 + 1024 * bc0;
  const float* bp1 = coeffs + (size_t)(n0 + br1) * 4096 + 1024 * bc1;
  const float* xp0 = x + (size_t)(row0 + lane) * IN_DIM + 128 * wv;
  const float* xp1 = xp0 + (size_t)64 * IN_DIM;

  for (int kt4 = 0; kt4 < 32; ++kt4) {
    float4 xa = *(const float4*)(xp0 + kt4 * 4);
    float4 xb = *(const float4*)(xp1 + kt4 * 4);
    float xr0[4] = {xa.x, xa.y, xa.z, xa.w};
    float xr1[4] = {xb.x, xb.y, xb.z, xb.w};
    #pragma unroll
    for (int j = 0; j < 4; ++j) {
      const int kt = kt4 * 4 + j;
      const float* s0 = bp0 + kt * 8;
      const float* s1 = bp1 + kt * 8;
      float4 b0a = *(const float4*)(s0), b0b = *(const float4*)(s0 + 4);
      float4 b1a = *(const float4*)(s1), b1b = *(const float4*)(s1 + 4);

      float2 c = Cs[128 * wv + kt];
      uint4 p0 = basis8(xr0[j], c.x, c.y);
      uint4 p1 = basis8(xr1[j], c.x, c.y);

      Bt[swz(br0, bc0)] = pk8(b0a, b0b);
      Bt[swz(br1, bc1)] = pk8(b1a, b1b);
      At[swz(lane, wv)]      = p0;
      At[swz(lane + 64, wv)] = p1;
      __syncthreads();
      do_mfma();
      __syncthreads();
    }
  }

  for (int kt = 0; kt < 16; ++kt) {
    const int k0 = kt * 32;
    const float* s0 = bwt + (size_t)(n0 + br0) * 512 + k0 + bc0 * 8;
    const float* s1 = bwt + (size_t)(n0 + br1) * 512 + k0 + bc1 * 8;
    float4 b0a = *(const float4*)(s0), b0b = *(const float4*)(s0 + 4);
    float4 b1a = *(const float4*)(s1), b1b = *(const float4*)(s1 + 4);

    uint4 p[2];
    #pragma unroll
    for (int rr = 0; rr < 2; ++rr) {
      int idx = tid + rr * 256;
      int r = idx >> 2, cch = idx & 3;
      const float* xs = x + (size_t)(row0 + r) * IN_DIM + k0 + cch * 8;
      float4 xc = *(const float4*)(xs), xd = *(const float4*)(xs + 4);
      float f[8] = {xc.x, xc.y, xc.z, xc.w, xd.x, xd.y, xd.z, xd.w};
      #pragma unroll
      for (int jj = 0; jj < 8; ++jj) f[jj] = f[jj] / (1.f + __expf(-f[jj]));
      p[rr].x = pk2(f[0], f[1]); p[rr].y = pk2(f[2], f[3]);
      p[rr].z = pk2(f[4], f[5]); p[rr].w = pk2(f[6], f[7]);
    }

    Bt[swz(br0, bc0)] = pk8(b0a, b0b);
    Bt[swz(br1, bc1)] = pk8(b1a, b1b);
    #pragma unroll
    for (int rr = 0; rr < 2; ++rr) {
      int idx = tid + rr * 256;
      At[swz(idx >> 2, idx & 3)] = p[rr];
    }
    __syncthreads();
    do_mfma();
    __syncthreads();
  }

  const float rs = rsc[0];
  #pragma unroll
  for (int tm = 0; tm < 4; ++tm) {
    #pragma unroll
    for (int tn = 0; tn < 4; ++tn) {
      #pragma unroll
      for (int r = 0; r < 4; ++r) {
        int m = row0 + wrow + tm * 16 + q * 4 + r;
        int n = n0 + wcol + tn * 16 + l15;
        float xv = x[(size_t)m * IN_DIM + n];
        float y  = acc[tm][tn][r] + rs * xv;
        float e  = __expf(-2.f * fabsf(y));
        float t  = copysignf((1.f - e) / (1.f + e), y);
        out[(size_t)m * OUT_DIM + n] = t;
      }
    }
  }
}

// ---------------------------------------------------------------------------
extern "C" void kernel_launch(void* const* d_in, const int* in_sizes, int n_in,
                              void* d_out, int out_size, void* d_ws, size_t ws_size,
                              hipStream_t stream) {
  const float* x      = (const float*)d_in[0];
  const float* coeffs = (const float*)d_in[1];
  const float* bwt    = (const float*)d_in[2];
  const float* gsl    = (const float*)d_in[3];
  const float* gstart = (const float*)d_in[4];
  const float* rsc    = (const float*)d_in[5];
  float* out = (float*)d_out;
  (void)in_sizes; (void)n_in; (void)out_size;

  const size_t needA = (size_t)BATCH * KCH * 16;     // 150,994,944 B
  const size_t needB = (size_t)OUT_DIM * KCH * 16;   //   4,718,592 B
  const size_t needC = (size_t)IN_DIM * 8;           //       4,096 B

  if (d_ws != nullptr && ws_size >= needA + needB + needC) {
    uint4*  A16 = (uint4*)d_ws;
    uint4*  B16 = (uint4*)((char*)d_ws + needA);
    float2* cst = (float2*)((char*)d_ws + needA + needB);
    hipLaunchKernelGGL(kan_consts, dim3(2), dim3(256), 0, stream,
                       gsl, gstart, cst);
    hipLaunchKernelGGL(kan_prep, dim3(8448), dim3(256), 0, stream,
                       x, coeffs, bwt, (const float2*)cst, A16, B16);
    hipLaunchKernelGGL(kan_gemm, dim3(512), dim3(256), 0, stream,
                       (const uint4*)A16, (const uint4*)B16, x, rsc, out);
  } else {
    hipLaunchKernelGGL(kan_main, dim3(4, 128), dim3(256), 0, stream,
                       x, coeffs, bwt, gsl, gstart, rsc, out);
  }
}